// Round 9
// baseline (763.270 us; speedup 1.0000x reference)
//
#include <hip/hip_runtime.h>

#define BLK 256
#define ABLK 512             // aggregation/shuffle block (8 waves)
#define PBLK 512
#define PITER 32
#define EPB (PBLK * PITER)   // 16384 edges per partition block
#define F_INK 18
#define F_HIDK 16
#define NPB 512              // nodes per bucket (src and dst)
#define NPB_SH 9
#define MAXNB 2048           // >= ceil(1e6/512)=1954
#define TPAD 17              // padded LDS accumulate stride (floats)

__device__ __forceinline__ unsigned f2bf(float f) {  // RNE f32->bf16 (finite inputs)
  unsigned u = __float_as_uint(f);
  return (u + 0x7fffu + ((u >> 16) & 1u)) >> 16;
}
__device__ __forceinline__ float bflo(unsigned u) { return __uint_as_float(u << 16); }
__device__ __forceinline__ float bfhi(unsigned u) { return __uint_as_float(u & 0xffff0000u); }

// ---------- dual histogram: dst-key and src-key counts matrices ----------
__global__ __launch_bounds__(PBLK) void k_hist2(const int* __restrict__ rows,
                                                const int* __restrict__ cols,
                                                int* __restrict__ cd, int* __restrict__ cs,
                                                int e, int NB, int nblk) {
  __shared__ int hd[MAXNB];
  __shared__ int hs[MAXNB];
  for (int j = threadIdx.x; j < NB; j += PBLK) { hd[j] = 0; hs[j] = 0; }
  __syncthreads();
  const int base = blockIdx.x * EPB;
#pragma unroll
  for (int k = 0; k < PITER; ++k) {
    int i = base + k * PBLK + threadIdx.x;
    if (i < e) {
      atomicAdd(&hd[__builtin_nontemporal_load(&cols[i]) >> NPB_SH], 1);
      atomicAdd(&hs[__builtin_nontemporal_load(&rows[i]) >> NPB_SH], 1);
    }
  }
  __syncthreads();
  for (int b = threadIdx.x; b < NB; b += PBLK) {
    cd[(size_t)b * nblk + blockIdx.x] = hd[b];
    cs[(size_t)b * nblk + blockIdx.x] = hs[b];
  }
}

// ---------- device-wide exclusive scan (L elements) ----------
__global__ void k_scanA(int* __restrict__ data, int* __restrict__ tot, int L) {
  __shared__ int sm[BLK];
  const int base = blockIdx.x * (BLK * 16) + threadIdx.x * 16;
  int v[16];
  int sum = 0;
#pragma unroll
  for (int j = 0; j < 16; ++j) {
    int idx = base + j;
    v[j] = (idx < L) ? data[idx] : 0;
    sum += v[j];
  }
  sm[threadIdx.x] = sum;
  __syncthreads();
  for (int off = 1; off < BLK; off <<= 1) {
    int t = (threadIdx.x >= off) ? sm[threadIdx.x - off] : 0;
    __syncthreads();
    sm[threadIdx.x] += t;
    __syncthreads();
  }
  int run = sm[threadIdx.x] - sum;
  if (threadIdx.x == BLK - 1) tot[blockIdx.x] = sm[BLK - 1];
#pragma unroll
  for (int j = 0; j < 16; ++j) {
    int idx = base + j;
    if (idx < L) data[idx] = run;
    run += v[j];
  }
}

__global__ void k_scanB(int* __restrict__ tot, int m) {  // single block, m <= 4096
  __shared__ int sm[BLK];
  const int base = threadIdx.x * 16;
  int v[16];
  int sum = 0;
#pragma unroll
  for (int j = 0; j < 16; ++j) {
    int idx = base + j;
    v[j] = (idx < m) ? tot[idx] : 0;
    sum += v[j];
  }
  sm[threadIdx.x] = sum;
  __syncthreads();
  for (int off = 1; off < BLK; off <<= 1) {
    int t = (threadIdx.x >= off) ? sm[threadIdx.x - off] : 0;
    __syncthreads();
    sm[threadIdx.x] += t;
    __syncthreads();
  }
  int run = sm[threadIdx.x] - sum;
#pragma unroll
  for (int j = 0; j < 16; ++j) {
    int idx = base + j;
    if (idx < m) tot[idx] = run;
    run += v[j];
  }
}

__global__ void k_scanC(int* __restrict__ data, const int* __restrict__ tot, int L) {
  const int add = tot[blockIdx.x];
  const int base = blockIdx.x * (BLK * 16) + threadIdx.x;
#pragma unroll
  for (int j = 0; j < 16; ++j) {
    int idx = base + j * BLK;
    if (idx < L) data[idx] += add;
  }
}

__global__ void k_bs(const int* __restrict__ counts, int* __restrict__ bs,
                     int NB, int nblk, int e) {
  int b = blockIdx.x * BLK + threadIdx.x;
  if (b < NB) bs[b] = counts[(size_t)b * nblk];
  if (b == 0) bs[NB] = e;
}

// ---------- dual fill: packed u32 (dst-order) + spos u32 (src-order) ----------
// packed = (dst & 511) << 20 | src        (n < 2^20)
// spos   = (src & 511) << 22 | dst_pos    (e <= 2^22)
__global__ __launch_bounds__(PBLK) void k_fill2(const int* __restrict__ rows,
                                                const int* __restrict__ cols,
                                                const int* __restrict__ cd,
                                                const int* __restrict__ cs,
                                                unsigned* __restrict__ packed,
                                                unsigned* __restrict__ spos,
                                                int e, int NB, int nblk) {
  __shared__ int curd[MAXNB];
  __shared__ int curs[MAXNB];
  for (int b = threadIdx.x; b < NB; b += PBLK) {
    curd[b] = cd[(size_t)b * nblk + blockIdx.x];
    curs[b] = cs[(size_t)b * nblk + blockIdx.x];
  }
  __syncthreads();
  const int base = blockIdx.x * EPB;
#pragma unroll
  for (int k = 0; k < PITER; ++k) {
    int i = base + k * PBLK + threadIdx.x;
    if (i < e) {
      int r = __builtin_nontemporal_load(&rows[i]);
      int c = __builtin_nontemporal_load(&cols[i]);
      int pd = atomicAdd(&curd[c >> NPB_SH], 1);
      packed[pd] = ((unsigned)(c & (NPB - 1)) << 20) | (unsigned)r;
      int ps = atomicAdd(&curs[r >> NPB_SH], 1);
      spos[ps] = ((unsigned)(r & (NPB - 1)) << 22) | (unsigned)pd;
    }
  }
}

// ---------- per-bucket degree -> dis = rsqrt(deg+1) ----------
__global__ __launch_bounds__(BLK) void k_bdeg(const unsigned* __restrict__ packed,
                                              const int* __restrict__ bs,
                                              float* __restrict__ dis, int n) {
  __shared__ int cnt[NPB];
  for (int j = threadIdx.x; j < NPB; j += BLK) cnt[j] = 0;
  __syncthreads();
  const int b = blockIdx.x;
  const int s = bs[b], t = bs[b + 1];
  for (int i = s + threadIdx.x; i < t; i += BLK) {
    unsigned pk = __builtin_nontemporal_load(&packed[i]);
    atomicAdd(&cnt[pk >> 20], 1);
  }
  __syncthreads();
  const int base = b << NPB_SH;
  for (int j = threadIdx.x; j < NPB; j += BLK) {
    int node = base + j;
    if (node < n) dis[node] = rsqrtf((float)(cnt[j] + 1));
  }
}

// ---------- node pass 1: s1 = bf16((x @ W1) * dis), 32 B/row ----------
__global__ void k_node1(const float* __restrict__ x, const float* __restrict__ W1,
                        const float* __restrict__ dis, uint4* __restrict__ s1b, int n) {
  __shared__ float sx[BLK * F_INK];
  const int base = blockIdx.x * BLK;
  const int gbase = base * F_INK;
  const int lim = n * F_INK;
  for (int t = threadIdx.x; t < BLK * F_INK; t += BLK) {
    int gi = gbase + t;
    sx[t] = (gi < lim) ? __builtin_nontemporal_load(&x[gi]) : 0.0f;
  }
  __syncthreads();
  int i = base + threadIdx.x;
  if (i >= n) return;
  float di = dis[i];
  float hw[F_HIDK];
#pragma unroll
  for (int f = 0; f < F_HIDK; ++f) hw[f] = 0.0f;
  const float* xi = &sx[threadIdx.x * F_INK];
#pragma unroll
  for (int k = 0; k < F_INK; ++k) {
    float xk = xi[k];
#pragma unroll
    for (int f = 0; f < F_HIDK; ++f) hw[f] = fmaf(xk, W1[k * F_HIDK + f], hw[f]);
  }
  unsigned w[8];
#pragma unroll
  for (int p = 0; p < 8; ++p)
    w[p] = f2bf(hw[2 * p] * di) | (f2bf(hw[2 * p + 1] * di) << 16);
  s1b[(size_t)i * 2 + 0] = make_uint4(w[0], w[1], w[2], w[3]);
  s1b[(size_t)i * 2 + 1] = make_uint4(w[4], w[5], w[6], w[7]);
}

// ---------- phase 1 (push): LDS src tile -> posted random 32B msg writes ----------
__global__ __launch_bounds__(ABLK) void k_phase1(const unsigned* __restrict__ spos,
                                                 const int* __restrict__ bss,
                                                 const int* __restrict__ bsd,
                                                 const uint4* __restrict__ s1b,
                                                 uint4* __restrict__ msg,
                                                 int cb_lo, int cb_hi, int n) {
  __shared__ uint4 tile[NPB * 2];  // 16 KB: this src bucket's s1 rows
  const int b = blockIdx.x;
  const int nbase = b << NPB_SH;
  const int nrow = min(NPB, n - nbase);
  for (int j = threadIdx.x; j < nrow * 2; j += ABLK)
    tile[j] = s1b[(size_t)nbase * 2 + j];
  __syncthreads();
  const int plo = bsd[cb_lo], phi = bsd[cb_hi];
  const int ss = bss[b], se = bss[b + 1];
  const int lane = threadIdx.x & 63;
  const int wid = threadIdx.x >> 6;   // 8 waves
  const int esub = lane >> 1;         // edge slot 0..31
  const int q = lane & 1;             // 16B half of the 32B row
  const int W = 32 * 4;               // 128 edges per wave-iter
  for (int base = ss + wid * W; base < se; base += 8 * W) {
    unsigned rec[4];
#pragma unroll
    for (int d = 0; d < 4; ++d) {
      int idx = base + d * 32 + esub;
      rec[d] = __builtin_nontemporal_load(&spos[min(idx, se - 1)]);
    }
#pragma unroll
    for (int d = 0; d < 4; ++d) {
      int idx = base + d * 32 + esub;
      int pd = (int)(rec[d] & 0x3FFFFFu);
      int rl = (int)(rec[d] >> 22);
      if (idx < se && pd >= plo && pd < phi)
        msg[(size_t)(pd - plo) * 2 + q] = tile[rl * 2 + q];
    }
  }
}

// ---------- phase 2 (pull, sequential): accumulate msg + fused node2 ----------
__global__ __launch_bounds__(ABLK) void k_phase2(const unsigned* __restrict__ packed,
                                                 const int* __restrict__ bsd,
                                                 const uint4* __restrict__ msg,
                                                 const uint4* __restrict__ s1b,
                                                 const float* __restrict__ dis,
                                                 const float* __restrict__ b1,
                                                 const float* __restrict__ W2,
                                                 float* __restrict__ s2,
                                                 int cb_lo, int n) {
  __shared__ float tile[NPB * TPAD];  // 34.8 KB, stride-17 -> conflict-light atomics
  for (int j = threadIdx.x; j < NPB * TPAD; j += ABLK) tile[j] = 0.0f;
  __syncthreads();
  const int b = cb_lo + blockIdx.x;
  const int plo = bsd[cb_lo];
  const int s = bsd[b], t = bsd[b + 1];
  const int lane = threadIdx.x & 63;
  const int wid = threadIdx.x >> 6;
  const int esub = lane >> 1;
  const int q = lane & 1;
  const int W = 32 * 4;
  for (int base = s + wid * W; base < t; base += 8 * W) {
    unsigned pk[4];
    uint4 m[4];
#pragma unroll
    for (int d = 0; d < 4; ++d) {
      int ci = min(base + d * 32 + esub, t - 1);
      pk[d] = __builtin_nontemporal_load(&packed[ci]);
      m[d] = msg[(size_t)(ci - plo) * 2 + q];   // sequential stream
    }
#pragma unroll
    for (int d = 0; d < 4; ++d) {
      int idx = base + d * 32 + esub;
      if (idx < t) {
        int c9 = (int)(pk[d] >> 20);
        float* tp = &tile[c9 * TPAD + q * 8];
        atomicAdd(tp + 0, bflo(m[d].x));
        atomicAdd(tp + 1, bfhi(m[d].x));
        atomicAdd(tp + 2, bflo(m[d].y));
        atomicAdd(tp + 3, bfhi(m[d].y));
        atomicAdd(tp + 4, bflo(m[d].z));
        atomicAdd(tp + 5, bfhi(m[d].z));
        atomicAdd(tp + 6, bflo(m[d].w));
        atomicAdd(tp + 7, bfhi(m[d].w));
      }
    }
  }
  __syncthreads();
  // fused node2 epilogue: h = relu(dis*(agg+self)+b1); s2 = (h@W2)*dis
  const int nbase = b << NPB_SH;
  for (int j = threadIdx.x; j < NPB; j += ABLK) {
    int node = nbase + j;
    if (node >= n) continue;
    float di = dis[node];
    uint4 a0 = s1b[(size_t)node * 2 + 0];
    uint4 a1 = s1b[(size_t)node * 2 + 1];
    float self[16] = {bflo(a0.x), bfhi(a0.x), bflo(a0.y), bfhi(a0.y),
                      bflo(a0.z), bfhi(a0.z), bflo(a0.w), bfhi(a0.w),
                      bflo(a1.x), bfhi(a1.x), bflo(a1.y), bfhi(a1.y),
                      bflo(a1.z), bfhi(a1.z), bflo(a1.w), bfhi(a1.w)};
    const float* tp = &tile[j * TPAD];
    float o0 = 0.f, o1 = 0.f;
#pragma unroll
    for (int f = 0; f < F_HIDK; ++f) {
      float h = fmaxf(fmaf(di, tp[f] + self[f], b1[f]), 0.0f);
      o0 = fmaf(h, W2[f * 2 + 0], o0);
      o1 = fmaf(h, W2[f * 2 + 1], o1);
    }
    float2 v;
    v.x = o0 * di;
    v.y = o1 * di;
    ((float2*)s2)[node] = v;
  }
}

// ---------- layer 2 aggregate: pipelined 8B gathers (8MB table) + log_softmax ----------
__global__ __launch_bounds__(ABLK) void k_agg2out(
    const unsigned* __restrict__ packed, const int* __restrict__ bs,
    const float* __restrict__ s2, const float* __restrict__ dis,
    const float* __restrict__ b2, float* __restrict__ out, int n) {
  __shared__ float t2[NPB * 3];
  for (int j = threadIdx.x; j < NPB * 3; j += ABLK) t2[j] = 0.0f;
  __syncthreads();
  const int b = blockIdx.x;
  const int s = bs[b], t = bs[b + 1];
  int i0 = s + threadIdx.x;
  if (i0 < t) {
    unsigned pk0 = __builtin_nontemporal_load(&packed[min(i0, t - 1)]);
    int i1 = i0 + ABLK;
    unsigned pk1 = (i1 < t) ? __builtin_nontemporal_load(&packed[min(i1, t - 1)]) : 0u;
    float2 v0 = ((const float2*)s2)[pk0 & 0xFFFFFu];
    while (i0 < t) {
      int i2 = i1 + ABLK;
      unsigned pk2 = (i2 < t) ? __builtin_nontemporal_load(&packed[min(i2, t - 1)]) : 0u;
      float2 v1 = ((const float2*)s2)[pk1 & 0xFFFFFu];
      {
        int c = (int)(pk0 >> 20);
        atomicAdd(&t2[c * 3 + 0], v0.x);
        atomicAdd(&t2[c * 3 + 1], v0.y);
      }
      pk0 = pk1; pk1 = pk2; v0 = v1;
      i0 = i1; i1 = i2;
    }
  }
  __syncthreads();
  const int nbase = b << NPB_SH;
  for (int j = threadIdx.x; j < NPB; j += ABLK) {
    int node = nbase + j;
    if (node >= n) continue;
    float di = dis[node];
    float2 sv = ((const float2*)s2)[node];
    float o0 = fmaf(di, t2[j * 3 + 0] + sv.x, b2[0]);
    float o1 = fmaf(di, t2[j * 3 + 1] + sv.y, b2[1]);
    float m = fmaxf(o0, o1);
    float lse = m + logf(expf(o0 - m) + expf(o1 - m));
    float2 r;
    r.x = o0 - lse;
    r.y = o1 - lse;
    ((float2*)out)[node] = r;
  }
}

extern "C" void kernel_launch(void* const* d_in, const int* in_sizes, int n_in,
                              void* d_out, int out_size, void* d_ws, size_t ws_size,
                              hipStream_t stream) {
  const float* x  = (const float*)d_in[0];
  const float* W1 = (const float*)d_in[1];
  const float* b1 = (const float*)d_in[2];
  const float* W2 = (const float*)d_in[3];
  const float* b2 = (const float*)d_in[4];
  const int*   ei = (const int*)d_in[5];
  const int n = in_sizes[0] / F_INK;
  const int e = in_sizes[5] / 2;
  const int* rows = ei;      // edge_index[0] = source
  const int* cols = ei + e;  // edge_index[1] = target

  const int NB = (n + NPB - 1) / NPB;    // 1954 buckets
  const int nblk = (e + EPB - 1) / EPB;  // 245 partition blocks
  const int L = NB * nblk;
  const int gA = (L + BLK * 16 - 1) / (BLK * 16);

  char* ws = (char*)d_ws;
  size_t off = 0;
  auto alloc = [&](size_t bytes) {
    void* p = ws + off;
    off = (off + bytes + 15) & ~(size_t)15;
    return p;
  };
  float* dis       = (float*)alloc((size_t)n * 4);
  uint4* s1b       = (uint4*)alloc((size_t)n * 32);   // bf16 s1, 32 B/row
  float* s2        = (float*)alloc((size_t)n * 2 * 4);
  unsigned* packed = (unsigned*)alloc((size_t)e * 4);
  unsigned* spos   = (unsigned*)alloc((size_t)e * 4);
  int* cd          = (int*)alloc((size_t)L * 4);
  int* cs          = (int*)alloc((size_t)L * 4);
  int* totd        = (int*)alloc((size_t)gA * 4);
  int* tots        = (int*)alloc((size_t)gA * 4);
  int* bsd         = (int*)alloc((size_t)(NB + 1) * 4);
  int* bss         = (int*)alloc((size_t)(NB + 1) * 4);
  uint4* msg       = (uint4*)(ws + ((off + 31) & ~(size_t)31));
  size_t cap_rows = (ws_size > off + 64) ? (ws_size - off - 64) / 32 : 0;  // 32B rows
  float* outp = (float*)d_out;

  // chunk over dst-bucket ranges so msg (32B per edge in range) fits workspace
  int nchunk = 1;
  while (nchunk < 256) {
    size_t need = (size_t)e / nchunk + e / (nchunk * 16) + 16384;
    if (need <= cap_rows) break;
    nchunk *= 2;
  }

  int gn = (n + BLK - 1) / BLK;

  k_hist2<<<nblk, PBLK, 0, stream>>>(rows, cols, cd, cs, e, NB, nblk);
  k_scanA<<<gA, BLK, 0, stream>>>(cd, totd, L);
  k_scanB<<<1, BLK, 0, stream>>>(totd, gA);
  k_scanC<<<gA, BLK, 0, stream>>>(cd, totd, L);
  k_scanA<<<gA, BLK, 0, stream>>>(cs, tots, L);
  k_scanB<<<1, BLK, 0, stream>>>(tots, gA);
  k_scanC<<<gA, BLK, 0, stream>>>(cs, tots, L);
  k_bs<<<(NB + BLK - 1) / BLK, BLK, 0, stream>>>(cd, bsd, NB, nblk, e);
  k_bs<<<(NB + BLK - 1) / BLK, BLK, 0, stream>>>(cs, bss, NB, nblk, e);
  k_fill2<<<nblk, PBLK, 0, stream>>>(rows, cols, cd, cs, packed, spos, e, NB, nblk);
  k_bdeg<<<NB, BLK, 0, stream>>>(packed, bsd, dis, n);
  k_node1<<<gn, BLK, 0, stream>>>(x, W1, dis, s1b, n);
  for (int j = 0; j < nchunk; ++j) {
    int cb_lo = (int)((long long)j * NB / nchunk);
    int cb_hi = (int)((long long)(j + 1) * NB / nchunk);
    if (cb_hi <= cb_lo) continue;
    k_phase1<<<NB, ABLK, 0, stream>>>(spos, bss, bsd, s1b, msg, cb_lo, cb_hi, n);
    k_phase2<<<cb_hi - cb_lo, ABLK, 0, stream>>>(packed, bsd, msg, s1b, dis, b1, W2,
                                                 s2, cb_lo, n);
  }
  k_agg2out<<<NB, ABLK, 0, stream>>>(packed, bsd, s2, dis, b2, outp, n);
}

// Round 10
// 306.441 us; speedup vs baseline: 2.4908x; 2.4908x over previous
//
#include <hip/hip_runtime.h>

#define BLK 256
#define ABLK 512             // aggregation block (8 waves)
#define PBLK 512
#define PITER 32
#define EPB (PBLK * PITER)   // 16384 edges per partition block
#define F_INK 18
#define F_HIDK 16
#define NPB 512              // nodes per dst bucket
#define NPB_SH 9
#define MAXNB 2048           // >= ceil(1e6/512)=1954
#define SBLK 512             // k_sort2 block (== NPB)

__device__ __forceinline__ unsigned f2bf(float f) {  // RNE f32->bf16 (finite inputs)
  unsigned u = __float_as_uint(f);
  return (u + 0x7fffu + ((u >> 16) & 1u)) >> 16;
}
__device__ __forceinline__ float bflo(unsigned u) { return __uint_as_float(u << 16); }
__device__ __forceinline__ float bfhi(unsigned u) { return __uint_as_float(u & 0xffff0000u); }

// ---------- histogram (dst-bucket key, bucket-major counts matrix) ----------
__global__ __launch_bounds__(PBLK) void k_hist(const int* __restrict__ cols,
                                               int* __restrict__ counts,
                                               int e, int NB, int nblk) {
  __shared__ int hist[MAXNB];
  for (int j = threadIdx.x; j < NB; j += PBLK) hist[j] = 0;
  __syncthreads();
  const int base = blockIdx.x * EPB;
#pragma unroll
  for (int k = 0; k < PITER; ++k) {
    int i = base + k * PBLK + threadIdx.x;
    if (i < e) atomicAdd(&hist[__builtin_nontemporal_load(&cols[i]) >> NPB_SH], 1);
  }
  __syncthreads();
  for (int b = threadIdx.x; b < NB; b += PBLK)
    counts[(size_t)b * nblk + blockIdx.x] = hist[b];
}

// ---------- device-wide exclusive scan (L elements) ----------
__global__ void k_scanA(int* __restrict__ data, int* __restrict__ tot, int L) {
  __shared__ int sm[BLK];
  const int base = blockIdx.x * (BLK * 16) + threadIdx.x * 16;
  int v[16];
  int sum = 0;
#pragma unroll
  for (int j = 0; j < 16; ++j) {
    int idx = base + j;
    v[j] = (idx < L) ? data[idx] : 0;
    sum += v[j];
  }
  sm[threadIdx.x] = sum;
  __syncthreads();
  for (int off = 1; off < BLK; off <<= 1) {
    int t = (threadIdx.x >= off) ? sm[threadIdx.x - off] : 0;
    __syncthreads();
    sm[threadIdx.x] += t;
    __syncthreads();
  }
  int run = sm[threadIdx.x] - sum;
  if (threadIdx.x == BLK - 1) tot[blockIdx.x] = sm[BLK - 1];
#pragma unroll
  for (int j = 0; j < 16; ++j) {
    int idx = base + j;
    if (idx < L) data[idx] = run;
    run += v[j];
  }
}

__global__ void k_scanB(int* __restrict__ tot, int m) {  // single block, m <= 4096
  __shared__ int sm[BLK];
  const int base = threadIdx.x * 16;
  int v[16];
  int sum = 0;
#pragma unroll
  for (int j = 0; j < 16; ++j) {
    int idx = base + j;
    v[j] = (idx < m) ? tot[idx] : 0;
    sum += v[j];
  }
  sm[threadIdx.x] = sum;
  __syncthreads();
  for (int off = 1; off < BLK; off <<= 1) {
    int t = (threadIdx.x >= off) ? sm[threadIdx.x - off] : 0;
    __syncthreads();
    sm[threadIdx.x] += t;
    __syncthreads();
  }
  int run = sm[threadIdx.x] - sum;
#pragma unroll
  for (int j = 0; j < 16; ++j) {
    int idx = base + j;
    if (idx < m) tot[idx] = run;
    run += v[j];
  }
}

__global__ void k_scanC(int* __restrict__ data, const int* __restrict__ tot, int L) {
  const int add = tot[blockIdx.x];
  const int base = blockIdx.x * (BLK * 16) + threadIdx.x;
#pragma unroll
  for (int j = 0; j < 16; ++j) {
    int idx = base + j * BLK;
    if (idx < L) data[idx] += add;
  }
}

__global__ void k_bs(const int* __restrict__ counts, int* __restrict__ bs,
                     int NB, int nblk, int e) {
  int b = blockIdx.x * BLK + threadIdx.x;
  if (b < NB) bs[b] = counts[(size_t)b * nblk];
  if (b == 0) bs[NB] = e;
}

// ---------- fill packed u32 records, dst-bucket-grouped ----------
// packed = (dst & 511) << 20 | src   (n < 2^20)
__global__ __launch_bounds__(PBLK) void k_fill(const int* __restrict__ rows,
                                               const int* __restrict__ cols,
                                               const int* __restrict__ counts,
                                               unsigned* __restrict__ packed,
                                               int e, int NB, int nblk) {
  __shared__ int cur[MAXNB];
  for (int b = threadIdx.x; b < NB; b += PBLK)
    cur[b] = counts[(size_t)b * nblk + blockIdx.x];
  __syncthreads();
  const int base = blockIdx.x * EPB;
#pragma unroll
  for (int k = 0; k < PITER; ++k) {
    int i = base + k * PBLK + threadIdx.x;
    if (i < e) {
      int r = __builtin_nontemporal_load(&rows[i]);
      int c = __builtin_nontemporal_load(&cols[i]);
      int p = atomicAdd(&cur[c >> NPB_SH], 1);
      packed[p] = ((unsigned)(c & (NPB - 1)) << 20) | (unsigned)r;
    }
  }
}

// ---------- second-level sort: exact-dst order + CSR offsets ----------
__global__ __launch_bounds__(SBLK) void k_sort2(const unsigned* __restrict__ packed,
                                                const int* __restrict__ bsd,
                                                unsigned* __restrict__ sorted2,
                                                int* __restrict__ nodeoff,
                                                int n, int e) {
  __shared__ int hist[NPB];
  __shared__ int basex[NPB];
  __shared__ int sm[SBLK];
  const int b = blockIdx.x;
  const int s = bsd[b], t = bsd[b + 1];
  hist[threadIdx.x] = 0;
  __syncthreads();
  for (int i = s + threadIdx.x; i < t; i += SBLK)
    atomicAdd(&hist[__builtin_nontemporal_load(&packed[i]) >> 20], 1);
  __syncthreads();
  // exclusive scan over 512 counters (SBLK == NPB)
  int v = hist[threadIdx.x];
  sm[threadIdx.x] = v;
  __syncthreads();
  for (int off = 1; off < SBLK; off <<= 1) {
    int tmp = (threadIdx.x >= off) ? sm[threadIdx.x - off] : 0;
    __syncthreads();
    sm[threadIdx.x] += tmp;
    __syncthreads();
  }
  basex[threadIdx.x] = sm[threadIdx.x] - v;
  int node = (b << NPB_SH) + threadIdx.x;
  if (node < n) nodeoff[node] = s + basex[threadIdx.x];
  if (b == gridDim.x - 1 && threadIdx.x == 0) nodeoff[n] = e;
  hist[threadIdx.x] = 0;  // reuse as cursor
  __syncthreads();
  for (int i = s + threadIdx.x; i < t; i += SBLK) {
    unsigned pk = __builtin_nontemporal_load(&packed[i]);
    int c9 = (int)(pk >> 20);
    int pos = atomicAdd(&hist[c9], 1);
    sorted2[(size_t)s + basex[c9] + pos] = pk & 0xFFFFFu;
  }
}

// ---------- node pass 1: dis from CSR degree; s1 = bf16((x @ W1) * dis) ----------
__global__ void k_node1(const float* __restrict__ x, const float* __restrict__ W1,
                        const int* __restrict__ nodeoff, float* __restrict__ dis,
                        uint4* __restrict__ s1b, int n) {
  __shared__ float sx[BLK * F_INK];
  const int base = blockIdx.x * BLK;
  const int gbase = base * F_INK;
  const int lim = n * F_INK;
  for (int t = threadIdx.x; t < BLK * F_INK; t += BLK) {
    int gi = gbase + t;
    sx[t] = (gi < lim) ? __builtin_nontemporal_load(&x[gi]) : 0.0f;
  }
  __syncthreads();
  int i = base + threadIdx.x;
  if (i >= n) return;
  float di = rsqrtf((float)(nodeoff[i + 1] - nodeoff[i] + 1));
  dis[i] = di;
  float hw[F_HIDK];
#pragma unroll
  for (int f = 0; f < F_HIDK; ++f) hw[f] = 0.0f;
  const float* xi = &sx[threadIdx.x * F_INK];
#pragma unroll
  for (int k = 0; k < F_INK; ++k) {
    float xk = xi[k];
#pragma unroll
    for (int f = 0; f < F_HIDK; ++f) hw[f] = fmaf(xk, W1[k * F_HIDK + f], hw[f]);
  }
  unsigned w[8];
#pragma unroll
  for (int p = 0; p < 8; ++p)
    w[p] = f2bf(hw[2 * p] * di) | (f2bf(hw[2 * p + 1] * di) << 16);
  s1b[(size_t)i * 2 + 0] = make_uint4(w[0], w[1], w[2], w[3]);
  s1b[(size_t)i * 2 + 1] = make_uint4(w[4], w[5], w[6], w[7]);
}

// ---------- layer 1: CSR run-walk, register accumulate (ZERO atomics) + node2 ----------
__global__ __launch_bounds__(ABLK) void k_agg1(const unsigned* __restrict__ sorted2,
                                               const int* __restrict__ nodeoff,
                                               const uint4* __restrict__ s1b,
                                               const float* __restrict__ dis,
                                               const float* __restrict__ b1,
                                               const float* __restrict__ W2,
                                               float* __restrict__ s2, int n) {
  const int q = threadIdx.x & 1;                       // 16B half of the 32B row
  const int node = blockIdx.x * (ABLK >> 1) + (threadIdx.x >> 1);
  if (node >= n) return;
  float di = dis[node];
  uint4 sv = s1b[(size_t)node * 2 + q];                // self term
  float acc[8] = {bflo(sv.x), bfhi(sv.x), bflo(sv.y), bfhi(sv.y),
                  bflo(sv.z), bfhi(sv.z), bflo(sv.w), bfhi(sv.w)};
  int i = nodeoff[node];
  const int re = nodeoff[node + 1];
  if (i < re) {
    uint4 v0 = s1b[(size_t)sorted2[i] * 2 + q];
    while (++i < re) {
      uint4 v1 = s1b[(size_t)sorted2[i] * 2 + q];      // prefetch next edge
      acc[0] += bflo(v0.x); acc[1] += bfhi(v0.x);
      acc[2] += bflo(v0.y); acc[3] += bfhi(v0.y);
      acc[4] += bflo(v0.z); acc[5] += bfhi(v0.z);
      acc[6] += bflo(v0.w); acc[7] += bfhi(v0.w);
      v0 = v1;
    }
    acc[0] += bflo(v0.x); acc[1] += bfhi(v0.x);
    acc[2] += bflo(v0.y); acc[3] += bfhi(v0.y);
    acc[4] += bflo(v0.z); acc[5] += bfhi(v0.z);
    acc[6] += bflo(v0.w); acc[7] += bfhi(v0.w);
  }
  // node2 epilogue: lane owns feats f = q*8+k; h = relu(di*acc+b1); o = h@W2
  float p0 = 0.f, p1 = 0.f;
#pragma unroll
  for (int k = 0; k < 8; ++k) {
    int f = q * 8 + k;
    float h = fmaxf(fmaf(di, acc[k], b1[f]), 0.0f);
    p0 = fmaf(h, W2[f * 2 + 0], p0);
    p1 = fmaf(h, W2[f * 2 + 1], p1);
  }
  p0 += __shfl_xor(p0, 1);
  p1 += __shfl_xor(p1, 1);
  if (q == 0) {
    float2 o;
    o.x = p0 * di;
    o.y = p1 * di;
    ((float2*)s2)[node] = o;
  }
}

// ---------- layer 2: CSR run-walk, register accumulate + log_softmax ----------
__global__ __launch_bounds__(ABLK) void k_agg2(const unsigned* __restrict__ sorted2,
                                               const int* __restrict__ nodeoff,
                                               const float* __restrict__ s2,
                                               const float* __restrict__ dis,
                                               const float* __restrict__ b2,
                                               float* __restrict__ out, int n) {
  const int node = blockIdx.x * ABLK + threadIdx.x;
  if (node >= n) return;
  float di = dis[node];
  float2 sv = ((const float2*)s2)[node];
  float a0 = sv.x, a1 = sv.y;
  int i = nodeoff[node];
  const int re = nodeoff[node + 1];
  if (i < re) {
    float2 v0 = ((const float2*)s2)[sorted2[i]];
    while (++i < re) {
      float2 v1 = ((const float2*)s2)[sorted2[i]];
      a0 += v0.x; a1 += v0.y;
      v0 = v1;
    }
    a0 += v0.x; a1 += v0.y;
  }
  float o0 = fmaf(di, a0, b2[0]);
  float o1 = fmaf(di, a1, b2[1]);
  float m = fmaxf(o0, o1);
  float lse = m + logf(expf(o0 - m) + expf(o1 - m));
  float2 r;
  r.x = o0 - lse;
  r.y = o1 - lse;
  ((float2*)out)[node] = r;
}

extern "C" void kernel_launch(void* const* d_in, const int* in_sizes, int n_in,
                              void* d_out, int out_size, void* d_ws, size_t ws_size,
                              hipStream_t stream) {
  const float* x  = (const float*)d_in[0];
  const float* W1 = (const float*)d_in[1];
  const float* b1 = (const float*)d_in[2];
  const float* W2 = (const float*)d_in[3];
  const float* b2 = (const float*)d_in[4];
  const int*   ei = (const int*)d_in[5];
  const int n = in_sizes[0] / F_INK;
  const int e = in_sizes[5] / 2;
  const int* rows = ei;      // edge_index[0] = source
  const int* cols = ei + e;  // edge_index[1] = target

  const int NB = (n + NPB - 1) / NPB;    // 1954 dst buckets
  const int nblk = (e + EPB - 1) / EPB;  // 245 partition blocks
  const int L = NB * nblk;
  const int gA = (L + BLK * 16 - 1) / (BLK * 16);

  char* ws = (char*)d_ws;
  size_t off = 0;
  auto alloc = [&](size_t bytes) {
    void* p = ws + off;
    off = (off + bytes + 15) & ~(size_t)15;
    return p;
  };
  float* dis        = (float*)alloc((size_t)n * 4);
  uint4* s1b        = (uint4*)alloc((size_t)n * 32);   // bf16 s1, 32 B/row
  float* s2         = (float*)alloc((size_t)n * 2 * 4);
  unsigned* packed  = (unsigned*)alloc((size_t)e * 4);
  unsigned* sorted2 = (unsigned*)alloc((size_t)e * 4);
  int* nodeoff      = (int*)alloc((size_t)(n + 1) * 4);
  int* counts       = (int*)alloc((size_t)L * 4);
  int* tot          = (int*)alloc((size_t)gA * 4);
  int* bsd          = (int*)alloc((size_t)(NB + 1) * 4);
  float* outp = (float*)d_out;

  int gn = (n + BLK - 1) / BLK;

  k_hist <<<nblk, PBLK, 0, stream>>>(cols, counts, e, NB, nblk);
  k_scanA<<<gA, BLK, 0, stream>>>(counts, tot, L);
  k_scanB<<<1, BLK, 0, stream>>>(tot, gA);
  k_scanC<<<gA, BLK, 0, stream>>>(counts, tot, L);
  k_bs   <<<(NB + BLK - 1) / BLK, BLK, 0, stream>>>(counts, bsd, NB, nblk, e);
  k_fill <<<nblk, PBLK, 0, stream>>>(rows, cols, counts, packed, e, NB, nblk);
  k_sort2<<<NB, SBLK, 0, stream>>>(packed, bsd, sorted2, nodeoff, n, e);
  k_node1<<<gn, BLK, 0, stream>>>(x, W1, nodeoff, dis, s1b, n);
  k_agg1 <<<(n + (ABLK / 2) - 1) / (ABLK / 2), ABLK, 0, stream>>>(sorted2, nodeoff, s1b,
                                                                  dis, b1, W2, s2, n);
  k_agg2 <<<(n + ABLK - 1) / ABLK, ABLK, 0, stream>>>(sorted2, nodeoff, s2, dis, b2,
                                                      outp, n);
}